// Round 13
// baseline (115.672 us; speedup 1.0000x reference)
//
#include <hip/hip_runtime.h>
#include <hip/hip_bf16.h>
#include <stdint.h>

// LePEAttention — R8 base + rpe fused into staging + SINGLE barrier.
// B=4, C=64, H=W=128, heads=8, hd=8, window=128x2 (256 toks).
// Grid 512: bid = ((b*8 + head)*2 + wjh)*8 + x  (x = XCD pin).
// Block = (b, head: 8ch, x, wjh: 4 windows), 512 threads = 8 waves:
// wave w -> window (w&3), q-half (w>>2).  launch_bounds(512,4).
// Phase collapse (R12): R8 had stage -> B -> preload -> B -> rpe -> B ->
// main (3 barriers, waves lock-stepped; R10 proved TLP is saturated, so
// the phase serialization IS the remaining stall). Now:
//   stage(+rpe in regs) -> ONE barrier -> preload -> main
// - rpe computed AT STAGING from the V registers: neighbor taps live in
//   lanes +-2 of the same wave (8 __shfl per window; iteration-boundary
//   toks from the adjacent i's registers; window edges -> 0). Deletes the
//   rpe phase's LDS V re-reads + its barrier.
// - rpe has its OWN LDS region (no k_s overlay) -> preload->rpe WAR
//   barrier gone. Nothing writes LDS after the single barrier.
// - conv weights read per-wave from global (ch = wave -> uniform
//   broadcast, conv_w is L2-resident); cw_s deleted.
// Math pipeline = R8 (43.3us): kf[16]+vf[16] in VGPRs, zero-LDS T-loop,
// XOR-swizzled tiles, MFMA-rsum (V A-row 8 = 1.0 -> denominator on the
// matrix pipe), dual PV accumulators, coalesced float4 staging.

typedef __attribute__((ext_vector_type(4))) short bf16x4;
typedef __attribute__((ext_vector_type(4))) float f32x4;

static __device__ __forceinline__ uint32_t pk2(float x, float y) {
    union { __hip_bfloat162 h2; uint32_t u; } c;
    c.h2 = __float22bfloat162_rn(make_float2(x, y));
    return c.u;
}
static __device__ __forceinline__ float bflo(uint32_t u){ return __uint_as_float(u<<16); }
static __device__ __forceinline__ float bfhi(uint32_t u){ return __uint_as_float(u & 0xffff0000u); }

// 8-byte LDS read at 4-byte alignment guarantee.
static __device__ __forceinline__ uint2 ld2(const char* p) {
    uint2 r;
    r.x = *(const uint32_t*)(p);
    r.y = *(const uint32_t*)(p + 4);
    return r;
}

// Swizzled byte offset of token row in a Q/K/rpe tile (16B payload rows).
static __device__ __forceinline__ int qk_off(int tok) {
    return (tok * 16) ^ ((tok >> 4 & 7) << 4);
}

static __device__ __forceinline__ f32x4 mfma16x16x16bf16(bf16x4 a, bf16x4 b, f32x4 c) {
#if __has_builtin(__builtin_amdgcn_mfma_f32_16x16x16bf16_1k)
    return __builtin_amdgcn_mfma_f32_16x16x16bf16_1k(a, b, c, 0, 0, 0);
#else
    f32x4 d;
    asm volatile("v_mfma_f32_16x16x16_bf16 %0, %1, %2, %3\n\ts_nop 7\n\ts_nop 7"
                 : "=v"(d) : "v"(a), "v"(b), "v"(c));
    return d;
#endif
}

// LDS layout (66688 B):
//   q_s:   [4 win][4128B: 256 tok x 16B swizzled + 32B pad]  16512 B @ 0
//   k_s:   same                                              16512 B @ 16512
//   rpe_s: same layout (bf16 conv output)                    16512 B @ 33024
//   v_t:   [4 win][8 ch][536B], tok t at byte 2t+4           17152 B @ 49536
#define QK_WIN_STR 4128
#define V_CH_STR   536
#define V_WIN_STR  4288

__global__ __launch_bounds__(512, 4)
void lepe_attn(const float* __restrict__ temp,
               const float* __restrict__ conv_w,
               const float* __restrict__ conv_b,
               float* __restrict__ out)
{
    __shared__ __align__(16) char smem[66688];
    char* q_s   = smem;
    char* k_s   = smem + 16512;
    char* rpe_s = smem + 33024;
    char* v_t   = smem + 49536;

    const int tid  = threadIdx.x;
    const int wave = tid >> 6, lane = tid & 63;
    const int lr = lane & 15, quad = lane >> 4;
    const int win   = wave & 3;          // window within the wjh quartet
    const int qbase = (wave >> 2) * 8;   // q-half: qg 0-7 or 8-15

    const int bid = blockIdx.x;
    const int x  = bid & 7;
    int t_ = bid >> 3;
    const int wjh  = t_ & 1;  t_ >>= 1;
    const int head = t_ & 7;
    const int b    = t_ >> 3;
    const int wi   = x*8 + wjh*4 + win;  // this wave's window index

    const size_t cstr = 16384, sstr = 64 * cstr;
    const float qs = 0.35355339059327373f * 1.4426950408889634f;  // hd^-0.5 * log2e

    // ---- staging + fused rpe: wave = channel; lane -> (h-group, half) ----
    {
        const int cg = wave;                 // channel within head
        const int hg = lane >> 1, hf1 = lane & 1;
        const int w0 = hf1 * 2;              // local window of this float4
        const float* bp = temp + (size_t)b*3*sstr + (size_t)(head*8 + cg)*cstr
                        + x*16 + wjh*8 + hf1*4;
        uint32_t p0[4], p1[4];               // packed V tok-pairs per window
        #pragma unroll
        for (int i = 0; i < 4; ++i) {
            int h = i*32 + hg;
            int o0 = qk_off(2*h), o1 = qk_off(2*h + 1);
            float4 fq = *(const float4*)(bp + (size_t)h*128);
            uint32_t a0 = pk2(fq.x*qs, fq.y*qs);
            uint32_t a1 = pk2(fq.z*qs, fq.w*qs);
            *(uint16_t*)(q_s + w0*QK_WIN_STR     + o0 + cg*2) = (uint16_t)a0;
            *(uint16_t*)(q_s + w0*QK_WIN_STR     + o1 + cg*2) = (uint16_t)(a0>>16);
            *(uint16_t*)(q_s + (w0+1)*QK_WIN_STR + o0 + cg*2) = (uint16_t)a1;
            *(uint16_t*)(q_s + (w0+1)*QK_WIN_STR + o1 + cg*2) = (uint16_t)(a1>>16);
            float4 fk = *(const float4*)(bp + sstr + (size_t)h*128);
            uint32_t b0 = pk2(fk.x, fk.y);
            uint32_t b1 = pk2(fk.z, fk.w);
            *(uint16_t*)(k_s + w0*QK_WIN_STR     + o0 + cg*2) = (uint16_t)b0;
            *(uint16_t*)(k_s + w0*QK_WIN_STR     + o1 + cg*2) = (uint16_t)(b0>>16);
            *(uint16_t*)(k_s + (w0+1)*QK_WIN_STR + o0 + cg*2) = (uint16_t)b1;
            *(uint16_t*)(k_s + (w0+1)*QK_WIN_STR + o1 + cg*2) = (uint16_t)(b1>>16);
            float4 fv = *(const float4*)(bp + 2*sstr + (size_t)h*128);
            p0[i] = pk2(fv.x, fv.y);
            p1[i] = pk2(fv.z, fv.w);
            *(uint32_t*)(v_t + w0*V_WIN_STR     + cg*V_CH_STR + 4*h + 4) = p0[i];
            *(uint32_t*)(v_t + (w0+1)*V_WIN_STR + cg*V_CH_STR + 4*h + 4) = p1[i];
        }
        // conv weights: ch = cg = wave-uniform -> broadcast loads, L2-hot.
        float w9[9];
        #pragma unroll
        for (int k = 0; k < 9; ++k) w9[k] = conv_w[head*72 + cg*9 + k];
        const float bia = conv_b[head*8 + cg];
        // fused rpe: neighbor tok-pairs via lane +-2 shuffles; iteration
        // boundaries from adjacent i's registers; window edges -> 0.
        #pragma unroll
        for (int wsel = 0; wsel < 2; ++wsel) {
            const uint32_t* p = wsel ? p1 : p0;
            char* rbase = rpe_s + (w0 + wsel)*QK_WIN_STR;
            uint32_t dn[4], up[4];
            #pragma unroll
            for (int i = 0; i < 4; ++i) {
                dn[i] = (uint32_t)__shfl((int)p[i], (lane - 2) & 63);
                up[i] = (uint32_t)__shfl((int)p[i], (lane + 2) & 63);
            }
            #pragma unroll
            for (int i = 0; i < 4; ++i) {
                int h = i*32 + hg;
                uint32_t pm  = (i > 0) ? dn[i-1] : 0u;
                uint32_t nx_ = (i < 3) ? up[i+1] : 0u;
                uint32_t prev = (lane < 2)  ? pm  : dn[i];
                uint32_t next = (lane >= 62) ? nx_ : up[i];
                float d0 = bflo(prev), d1 = bfhi(prev);
                float d2 = bflo(p[i]), d3 = bfhi(p[i]);
                float d4 = bflo(next), d5 = bfhi(next);
                float e = bia, o = bia;
                e = fmaf(w9[1], d0, e); o = fmaf(w9[0], d0, o);
                e = fmaf(w9[2], d1, e); o = fmaf(w9[1], d1, o);
                e = fmaf(w9[4], d2, e); o = fmaf(w9[3], d2, o);
                e = fmaf(w9[5], d3, e); o = fmaf(w9[4], d3, o);
                e = fmaf(w9[7], d4, e); o = fmaf(w9[6], d4, o);
                e = fmaf(w9[8], d5, e); o = fmaf(w9[7], d5, o);
                uint32_t eo = pk2(e, o);
                *(uint16_t*)(rbase + qk_off(2*h)   + cg*2) = (uint16_t)eo;
                *(uint16_t*)(rbase + qk_off(2*h+1) + cg*2) = (uint16_t)(eo >> 16);
            }
        }
    }
    __syncthreads();   // the ONLY barrier: all LDS writes complete here.

    // ---- preload K A-frags and V A-frags into VGPRs ----
    const f32x4 zf = {0.f, 0.f, 0.f, 0.f};
    const uint2 z2 = make_uint2(0, 0);
    const uint2 ones2 = make_uint2(0x3F803F80u, 0x3F803F80u);  // 4x bf16 1.0
    uint2 kf[16]; uint2 vf[16];
    #pragma unroll
    for (int T = 0; T < 16; ++T) {
        uint2 kk = ld2(k_s + win*QK_WIN_STR + qk_off(T*16 + lr) + (quad & 1)*8);
        kf[T] = (quad < 2) ? kk : z2;
        uint2 vv = ld2(v_t + win*V_WIN_STR + (lane & 7)*V_CH_STR + 4 + (T*16 + quad*4)*2);
        // row 8 = ones channel: PV acc row 8 accumulates sum(exp) per q-col.
        vf[T] = (lr < 8) ? vv : ((lr == 8) ? ones2 : z2);
    }

    // ---- main: per q-group: S^T mfma -> exp -> pack -> PV mfma (chained) ----
    #pragma unroll 1
    for (int qg0 = 0; qg0 < 8; ++qg0) {
        const int qg = qbase + qg0;
        uint2 qq = ld2(q_s + win*QK_WIN_STR + qk_off(qg*16 + lr) + (quad & 1)*8);
        union { uint2 u; bf16x4 h4; } qf; qf.u = (quad < 2) ? qq : z2;
        f32x4 acc0 = zf, acc1 = zf;   // dual acc: halves the PV dep chain
        #pragma unroll
        for (int T = 0; T < 16; T += 2) {
            union { uint2 u; bf16x4 h4; } kfu0; kfu0.u = kf[T];
            union { uint2 u; bf16x4 h4; } kfu1; kfu1.u = kf[T+1];
            f32x4 sc0 = mfma16x16x16bf16(kfu0.h4, qf.h4, zf);
            f32x4 sc1 = mfma16x16x16bf16(kfu1.h4, qf.h4, zf);
            float a0 = __builtin_amdgcn_exp2f(sc0[0]);
            float a1 = __builtin_amdgcn_exp2f(sc0[1]);
            float a2 = __builtin_amdgcn_exp2f(sc0[2]);
            float a3 = __builtin_amdgcn_exp2f(sc0[3]);
            float b0_ = __builtin_amdgcn_exp2f(sc1[0]);
            float b1_ = __builtin_amdgcn_exp2f(sc1[1]);
            float b2_ = __builtin_amdgcn_exp2f(sc1[2]);
            float b3_ = __builtin_amdgcn_exp2f(sc1[3]);
            union { uint2 u; bf16x4 h4; } pb0; pb0.u = make_uint2(pk2(a0,a1), pk2(a2,a3));
            union { uint2 u; bf16x4 h4; } pb1; pb1.u = make_uint2(pk2(b0_,b1_), pk2(b2_,b3_));
            union { uint2 u; bf16x4 h4; } vf0; vf0.u = vf[T];
            union { uint2 u; bf16x4 h4; } vf1; vf1.u = vf[T+1];
            acc0 = mfma16x16x16bf16(vf0.h4, pb0.h4, acc0);
            acc1 = mfma16x16x16bf16(vf1.h4, pb1.h4, acc1);
        }
        f32x4 acc;
        acc[0] = acc0[0] + acc1[0];
        acc[1] = acc0[1] + acc1[1];
        acc[2] = acc0[2] + acc1[2];
        acc[3] = acc0[3] + acc1[3];
        // sum(exp) is acc[0] of quad-2 lanes (PV D row 8), col = lr.
        float rs = __shfl(acc[0], 32 + lr);
        const float rinv = __builtin_amdgcn_rcpf(rs);
        if (quad < 2) {
            int tok = qg*16 + lr;
            int h = tok >> 1, w01 = tok & 1;
            uint2 rp2 = ld2(rpe_s + win*QK_WIN_STR + qk_off(tok) + quad*8);
            float4 ov;
            ov.x = fmaf(acc[0], rinv, bflo(rp2.x));
            ov.y = fmaf(acc[1], rinv, bfhi(rp2.x));
            ov.z = fmaf(acc[2], rinv, bflo(rp2.y));
            ov.w = fmaf(acc[3], rinv, bfhi(rp2.y));
            size_t addr = (size_t)b*1048576 + (size_t)(h*128 + wi*2 + w01)*64
                        + head*8 + quad*4;
            *(float4*)(out + addr) = ov;
        }
    }
}

extern "C" void kernel_launch(void* const* d_in, const int* in_sizes, int n_in,
                              void* d_out, int out_size, void* d_ws, size_t ws_size,
                              hipStream_t stream) {
    const float* temp = (const float*)d_in[0];
    const float* cw   = (const float*)d_in[1];
    const float* cb   = (const float*)d_in[2];
    float* o = (float*)d_out;
    (void)in_sizes; (void)n_in; (void)out_size; (void)d_ws; (void)ws_size;
    lepe_attn<<<dim3(512), dim3(512), 0, stream>>>(temp, cw, cb, o);
}